// Round 3
// baseline (973.435 us; speedup 1.0000x reference)
//
#include <hip/hip_runtime.h>
#include <hip/hip_bf16.h>
#include <math.h>

#define D_MODEL 1024
#define VOCAB   50257
#define VPAD    50304   // VOCAB padded to multiple of 128
#define N_TOK   2048
#define PAD_ID  1

typedef __attribute__((ext_vector_type(8))) short bf16x8;
typedef __attribute__((ext_vector_type(4))) float f32x4;
typedef __attribute__((ext_vector_type(2))) unsigned int u32x2;
typedef __attribute__((ext_vector_type(4))) unsigned short u16x4;

// f32 -> bf16 (round-half-up), pack 2 into u32.
static __device__ __forceinline__ unsigned int pack2bf(float a, float b) {
  unsigned int ua = (__float_as_uint(a) + 0x8000u) >> 16;
  unsigned int ub = (__float_as_uint(b) + 0x8000u) & 0xffff0000u;
  return ua | ub;
}
static __device__ __forceinline__ unsigned short bf16of(float a) {
  return (unsigned short)((__float_as_uint(a) + 0x8000u) >> 16);
}

static __device__ __forceinline__ void gload_lds16(const void* g, void* l) {
  __builtin_amdgcn_global_load_lds(
      (const __attribute__((address_space(1))) void*)g,
      (__attribute__((address_space(3))) void*)l, 16, 0, 0);
}

// ---------------- prepass: f32 -> bf16 (flat, n % 4 == 0) ----------------
__global__ __launch_bounds__(256)
void cvt_f32_bf16(const float* __restrict__ in, unsigned short* __restrict__ out, int n4) {
  for (int i = blockIdx.x * blockDim.x + threadIdx.x; i < n4; i += gridDim.x * blockDim.x) {
    f32x4 v = *(const f32x4*)(in + 4 * (size_t)i);
    u16x4 o;
    o[0] = bf16of(v[0]); o[1] = bf16of(v[1]); o[2] = bf16of(v[2]); o[3] = bf16of(v[3]);
    *(u16x4*)(out + 4 * (size_t)i) = o;
  }
}

// zero the padded W rows (deterministic pad; don't rely on harness poison value)
__global__ __launch_bounds__(256)
void zero_pad_rows(unsigned short* __restrict__ out, int n4) {
  int i = blockIdx.x * blockDim.x + threadIdx.x;
  if (i < n4) {
    u16x4 z = {0, 0, 0, 0};
    *(u16x4*)(out + 4 * (size_t)i) = z;
  }
}

// ---------------- fast GEMM: bf16 inputs, global_load_lds staging ----------------
// scores[m][n] = sum_d X[m][d]*W[n][d] + bias[n]
// 128x128 tile, BK=32, 4 waves (2x2 of 64x64), mfma_f32_16x16x32_bf16. m97 structure.
__global__ __launch_bounds__(256)
void gemm_scores_bf16(const unsigned short* __restrict__ Xb, const unsigned short* __restrict__ Wb,
                      const float* __restrict__ bias, float* __restrict__ OUT)
{
  const int tid  = threadIdx.x;
  const int lane = tid & 63;
  const int wave = tid >> 6;
  const int m0 = blockIdx.y * 128;
  const int n0 = blockIdx.x * 128;
  const int wm = (wave >> 1) * 64;
  const int wn = (wave & 1) * 64;

  __shared__ __attribute__((aligned(16))) unsigned short As[128 * 32];
  __shared__ __attribute__((aligned(16))) unsigned short Bs[128 * 32];

  f32x4 acc[4][4] = {};

  const int frow = lane & 15;
  const int fk   = (lane >> 4) * 8;

  // staging geometry: per wave, 2 instructions per operand per tile; instruction
  // (w,i) covers rows [w*32 + i*16, +16); lane l -> row + (l>>2), shorts (l&3)*8.
  // Linear LDS dest: base + lane*16B == shorts r*32 + l*8 == row-major [128][32]. (m97)
  const int srow = (lane >> 2);          // 0..15
  const int scol = (lane & 3) * 8;       // shorts

  for (int kt = 0; kt < D_MODEL / 32; ++kt) {
    const int k0 = kt * 32;

    __syncthreads();   // WAR: previous iteration's fragment reads done

#pragma unroll
    for (int i = 0; i < 2; ++i) {
      const int r = wave * 32 + i * 16;
      gload_lds16(Xb + (size_t)(m0 + r + srow) * D_MODEL + k0 + scol, &As[r * 32]);
      gload_lds16(Wb + (size_t)(n0 + r + srow) * D_MODEL + k0 + scol, &Bs[r * 32]);
    }

    __syncthreads();   // compiler drains vmcnt(0) before s_barrier: tiles visible

    bf16x8 afrag[4], bfrag[4];
#pragma unroll
    for (int i = 0; i < 4; ++i)
      afrag[i] = *(const bf16x8*)&As[(wm + i * 16 + frow) * 32 + fk];
#pragma unroll
    for (int j = 0; j < 4; ++j)
      bfrag[j] = *(const bf16x8*)&Bs[(wn + j * 16 + frow) * 32 + fk];

#pragma unroll
    for (int i = 0; i < 4; ++i)
#pragma unroll
      for (int j = 0; j < 4; ++j)
        acc[i][j] = __builtin_amdgcn_mfma_f32_16x16x32_bf16(afrag[i], bfrag[j], acc[i][j], 0, 0, 0);
  }

  // C/D layout: col=lane&15, row=(lane>>4)*4+reg (m89-verified)
  const int r4 = (lane >> 4) << 2;
  const int cc = lane & 15;
#pragma unroll
  for (int j = 0; j < 4; ++j) {
    const int col = n0 + wn + j * 16 + cc;
    if (col < VOCAB) {
      const float bj = bias[col];
#pragma unroll
      for (int i = 0; i < 4; ++i) {
        const int row = m0 + wm + i * 16 + r4;
        float* o = OUT + (size_t)row * VOCAB + col;
#pragma unroll
        for (int r = 0; r < 4; ++r)
          o[(size_t)r * VOCAB] = acc[i][j][r] + bj;
      }
    }
  }
}

// ---------------- fallback GEMM: f32 inputs, reg-staged ----------------
__global__ __launch_bounds__(256)
void gemm_scores(const float* __restrict__ X, const float* __restrict__ W,
                 const float* __restrict__ bias, float* __restrict__ OUT)
{
  const int tid  = threadIdx.x;
  const int lane = tid & 63;
  const int wave = tid >> 6;
  const int m0 = blockIdx.y * 128;
  const int n0 = blockIdx.x * 128;
  const int wm = (wave >> 1) * 64;
  const int wn = (wave & 1) * 64;

  __shared__ __attribute__((aligned(16))) unsigned short As[128 * 32];
  __shared__ __attribute__((aligned(16))) unsigned short Bs[128 * 32];

  f32x4 acc[4][4] = {};

  const int frow = lane & 15;
  const int fk   = (lane >> 4) * 8;

  for (int kt = 0; kt < D_MODEL / 32; ++kt) {
    const int k0 = kt * 32;
    f32x4 av[4], bv[4];
#pragma unroll
    for (int i = 0; i < 4; ++i) {
      const int idx = tid + (i << 8);
      const int r = idx >> 3;
      const int c = (idx & 7) << 2;
      av[i] = *(const f32x4*)(X + (size_t)(m0 + r) * D_MODEL + k0 + c);
      int wr = n0 + r; if (wr > VOCAB - 1) wr = VOCAB - 1;
      bv[i] = *(const f32x4*)(W + (size_t)wr * D_MODEL + k0 + c);
    }
    __syncthreads();
#pragma unroll
    for (int i = 0; i < 4; ++i) {
      const int idx = tid + (i << 8);
      const int r = idx >> 3;
      const int c = (idx & 7) << 2;
      u32x2 pa, pb;
      pa[0] = pack2bf(av[i][0], av[i][1]);
      pa[1] = pack2bf(av[i][2], av[i][3]);
      pb[0] = pack2bf(bv[i][0], bv[i][1]);
      pb[1] = pack2bf(bv[i][2], bv[i][3]);
      *(u32x2*)&As[r * 32 + c] = pa;
      *(u32x2*)&Bs[r * 32 + c] = pb;
    }
    __syncthreads();

    bf16x8 afrag[4], bfrag[4];
#pragma unroll
    for (int i = 0; i < 4; ++i)
      afrag[i] = *(const bf16x8*)&As[(wm + i * 16 + frow) * 32 + fk];
#pragma unroll
    for (int j = 0; j < 4; ++j)
      bfrag[j] = *(const bf16x8*)&Bs[(wn + j * 16 + frow) * 32 + fk];
#pragma unroll
    for (int i = 0; i < 4; ++i)
#pragma unroll
      for (int j = 0; j < 4; ++j)
        acc[i][j] = __builtin_amdgcn_mfma_f32_16x16x32_bf16(afrag[i], bfrag[j], acc[i][j], 0, 0, 0);
  }

  const int r4 = (lane >> 4) << 2;
  const int cc = lane & 15;
#pragma unroll
  for (int j = 0; j < 4; ++j) {
    const int col = n0 + wn + j * 16 + cc;
    if (col < VOCAB) {
      const float bj = bias[col];
#pragma unroll
      for (int i = 0; i < 4; ++i) {
        const int row = m0 + wm + i * 16 + r4;
        float* o = OUT + (size_t)row * VOCAB + col;
#pragma unroll
        for (int r = 0; r < 4; ++r)
          o[(size_t)r * VOCAB] = acc[i][j][r] + bj;
      }
    }
  }
}

// ---------------- row stats + loss ----------------
__global__ __launch_bounds__(256)
void row_stats_loss(const float* __restrict__ S, const int* __restrict__ labels,
                    float* __restrict__ loss)
{
  const int row = blockIdx.x;
  const int tid = threadIdx.x;
  const float* p = S + (size_t)row * VOCAB;

  float m = -INFINITY, s = 0.f, tot = 0.f;

  const int head = (4 - (row & 3)) & 3;   // (row*VOCAB)%4 == row%4
  if (tid < head) {
    float x = p[tid];
    tot = x; m = x; s = 1.f;
  }
  const int nvec = (VOCAB - head) >> 2;
  const float* pv = p + head;
  for (int i = tid; i < nvec; i += 256) {
    f32x4 x4 = *(const f32x4*)(pv + 4 * i);
#pragma unroll
    for (int e = 0; e < 4; ++e) {
      float x = x4[e];
      tot += x;
      float nm = fmaxf(m, x);
      if (nm > m) { s *= __expf(m - nm); m = nm; }
      s += __expf(x - m);
    }
  }
  const int tbase = head + 4 * nvec;
  if (tid < VOCAB - tbase) {
    float x = p[tbase + tid];
    tot += x;
    float nm = fmaxf(m, x);
    if (nm > m) { s *= __expf(m - nm); m = nm; }
    s += __expf(x - m);
  }

#pragma unroll
  for (int off = 1; off < 64; off <<= 1) {
    float om = __shfl_xor(m, off);
    float os = __shfl_xor(s, off);
    tot += __shfl_xor(tot, off);
    float nm = fmaxf(m, om);
    s = s * __expf(m - nm) + os * __expf(om - nm);
    m = nm;
  }

  __shared__ float red[12];
  const int wave = tid >> 6;
  if ((tid & 63) == 0) { red[wave] = m; red[4 + wave] = s; red[8 + wave] = tot; }
  __syncthreads();

  if (tid == 0) {
    m = red[0]; s = red[4]; tot = red[8];
    for (int w = 1; w < 4; ++w) {
      float om = red[w], os = red[4 + w];
      float nm = fmaxf(m, om);
      s = s * __expf(m - nm) + os * __expf(om - nm);
      m = nm;
      tot += red[8 + w];
    }
    const int lbl = labels[row];
    if (lbl != PAD_ID) {
      const float x_lbl = p[lbl];
      const float x_pad = p[PAD_ID];
      const float logZ = m + logf(s);
      const float sv   = 0.1f / (float)(VOCAB - 2);
      const float conf = 0.9f;
      const float plogp = 0.1f * logf(sv) + conf * logf(conf);  // sum p*log p, const per non-pad row
      const float plogq = sv * (tot - x_pad - x_lbl) + conf * x_lbl - logZ;
      atomicAdd(loss, (plogp - plogq) * (1.0f / N_TOK));
    }
  }
}

__global__ void zero_loss(float* loss) { *loss = 0.f; }

extern "C" void kernel_launch(void* const* d_in, const int* in_sizes, int n_in,
                              void* d_out, int out_size, void* d_ws, size_t ws_size,
                              hipStream_t stream) {
  const float* X      = (const float*)d_in[0];
  const float* W      = (const float*)d_in[1];
  const float* bias   = (const float*)d_in[2];
  const int*   labels = (const int*)d_in[3];
  float* out  = (float*)d_out;
  float* loss = out + (size_t)N_TOK * VOCAB;

  zero_loss<<<1, 1, 0, stream>>>(loss);

  const size_t wb_elems = (size_t)VPAD * D_MODEL;
  const size_t xb_elems = (size_t)N_TOK * D_MODEL;
  const size_t need = (wb_elems + xb_elems) * sizeof(unsigned short);

  dim3 grid(VPAD / 128, N_TOK / 128);   // 393 x 16

  if (ws_size >= need) {
    unsigned short* Wb = (unsigned short*)d_ws;
    unsigned short* Xb = Wb + wb_elems;
    cvt_f32_bf16<<<2048, 256, 0, stream>>>(W, Wb, (int)((size_t)VOCAB * D_MODEL / 4));
    {
      const int padn4 = (int)(((size_t)(VPAD - VOCAB) * D_MODEL) / 4);  // 47*1024/4 = 12032
      zero_pad_rows<<<(padn4 + 255) / 256, 256, 0, stream>>>(Wb + (size_t)VOCAB * D_MODEL, padn4);
    }
    cvt_f32_bf16<<<512, 256, 0, stream>>>(X, Xb, (int)(xb_elems / 4));
    gemm_scores_bf16<<<grid, 256, 0, stream>>>(Xb, Wb, bias, out);
  } else {
    gemm_scores<<<grid, 256, 0, stream>>>(X, W, bias, out);
  }

  row_stats_loss<<<N_TOK, 256, 0, stream>>>(out, labels, loss);
}

// Round 12
// 931.810 us; speedup vs baseline: 1.0447x; 1.0447x over previous
//
#include <hip/hip_runtime.h>
#include <hip/hip_bf16.h>
#include <math.h>

#define D_MODEL 1024
#define VOCAB   50257
#define VPAD    50304   // VOCAB padded to multiple of 128
#define N_TOK   2048
#define PAD_ID  1
#define NTILE   (VPAD / 128)    // 393
#define MTILE   (N_TOK / 128)   // 16
#define NWG     (NTILE * MTILE) // 6288
#define CPX     (NWG / 8)       // 786 blocks per XCD chunk

typedef __attribute__((ext_vector_type(8))) short bf16x8;
typedef __attribute__((ext_vector_type(4))) float f32x4;
typedef __attribute__((ext_vector_type(2))) unsigned int u32x2;
typedef __attribute__((ext_vector_type(4))) unsigned short u16x4;

static __device__ __forceinline__ unsigned int pack2bf(float a, float b) {
  unsigned int ua = (__float_as_uint(a) + 0x8000u) >> 16;
  unsigned int ub = (__float_as_uint(b) + 0x8000u) & 0xffff0000u;
  return ua | ub;
}
static __device__ __forceinline__ unsigned short bf16of(float a) {
  return (unsigned short)((__float_as_uint(a) + 0x8000u) >> 16);
}

static __device__ __forceinline__ void gload_lds16(const void* g, void* l) {
  __builtin_amdgcn_global_load_lds(
      (const __attribute__((address_space(1))) void*)g,
      (__attribute__((address_space(3))) void*)l, 16, 0, 0);
}

// ---------------- prepass: f32 -> bf16 ----------------
__global__ __launch_bounds__(256)
void cvt_f32_bf16(const float* __restrict__ in, unsigned short* __restrict__ out, int n4) {
  for (int i = blockIdx.x * blockDim.x + threadIdx.x; i < n4; i += gridDim.x * blockDim.x) {
    f32x4 v = *(const f32x4*)(in + 4 * (size_t)i);
    u16x4 o;
    o[0] = bf16of(v[0]); o[1] = bf16of(v[1]); o[2] = bf16of(v[2]); o[3] = bf16of(v[3]);
    *(u16x4*)(out + 4 * (size_t)i) = o;
  }
}

__global__ __launch_bounds__(256)
void zero_pad_rows(unsigned short* __restrict__ out, int n4) {
  int i = blockIdx.x * blockDim.x + threadIdx.x;
  if (i < n4) {
    u16x4 z = {0, 0, 0, 0};
    *(u16x4*)(out + 4 * (size_t)i) = z;
  }
}

// ---------------- fused GEMM + row-stat partials ----------------
// scores[m][n] = sum_d X[m][d]*W[n][d] + bias[n]; per-block per-row {max, sumexp, sum}
// over the block's 128 cols -> partial[row][n_tile]. m97 structure, XCD-chunked swizzle.
__global__ __launch_bounds__(256)
void gemm_scores_fused(const unsigned short* __restrict__ Xb, const unsigned short* __restrict__ Wb,
                       const float* __restrict__ bias, float* __restrict__ OUT,
                       f32x4* __restrict__ partial)
{
  const int tid  = threadIdx.x;
  const int lane = tid & 63;
  const int wave = tid >> 6;

  // XCD-chunked swizzle (T1): each XCD gets a contiguous run of tiles, m-tile fastest
  // so the 16 blocks sharing one W panel co-reside on one XCD's L2.
  const int bid = blockIdx.x;
  const int sw  = (bid & 7) * CPX + (bid >> 3);   // bijective: NWG % 8 == 0
  const int m0     = (sw & 15) * 128;
  const int n_tile = sw >> 4;
  const int n0     = n_tile * 128;

  const int wm = (wave >> 1) * 64;
  const int wn = (wave & 1) * 64;

  __shared__ __attribute__((aligned(16))) unsigned short As[128 * 32];
  __shared__ __attribute__((aligned(16))) unsigned short Bs[128 * 32];
  __shared__ f32x4 sred[128][2];

  f32x4 acc[4][4] = {};

  const int frow = lane & 15;
  const int fk   = (lane >> 4) * 8;
  const int srow = (lane >> 2);
  const int scol = (lane & 3) * 8;

  for (int kt = 0; kt < D_MODEL / 32; ++kt) {
    const int k0 = kt * 32;

    __syncthreads();   // WAR: previous iteration's fragment reads done

#pragma unroll
    for (int i = 0; i < 2; ++i) {
      const int r = wave * 32 + i * 16;
      gload_lds16(Xb + (size_t)(m0 + r + srow) * D_MODEL + k0 + scol, &As[r * 32]);
      gload_lds16(Wb + (size_t)(n0 + r + srow) * D_MODEL + k0 + scol, &Bs[r * 32]);
    }

    __syncthreads();   // vmcnt(0) drained before barrier: tiles visible

    bf16x8 afrag[4], bfrag[4];
#pragma unroll
    for (int i = 0; i < 4; ++i)
      afrag[i] = *(const bf16x8*)&As[(wm + i * 16 + frow) * 32 + fk];
#pragma unroll
    for (int j = 0; j < 4; ++j)
      bfrag[j] = *(const bf16x8*)&Bs[(wn + j * 16 + frow) * 32 + fk];

#pragma unroll
    for (int i = 0; i < 4; ++i)
#pragma unroll
      for (int j = 0; j < 4; ++j)
        acc[i][j] = __builtin_amdgcn_mfma_f32_16x16x32_bf16(afrag[i], bfrag[j], acc[i][j], 0, 0, 0);
  }

  // ---- epilogue: bias add, store scores, per-row stats over this block's cols
  // C/D layout: col=lane&15, row=(lane>>4)*4+reg (m89-verified)
  const int r4 = (lane >> 4) << 2;
  const int cc = lane & 15;

  float bj[4];
  bool  vld[4];
#pragma unroll
  for (int j = 0; j < 4; ++j) {
    const int col = n0 + wn + j * 16 + cc;
    vld[j] = (col < VOCAB);
    bj[j] = vld[j] ? bias[col] : 0.f;
  }

#pragma unroll
  for (int i = 0; i < 4; ++i) {
    const int rowl = wm + i * 16 + r4;   // local row base for this (i, lane-group)
#pragma unroll
    for (int r = 0; r < 4; ++r) {
      float v[4];
#pragma unroll
      for (int j = 0; j < 4; ++j) v[j] = acc[i][j][r] + bj[j];

      // store scores (predicated on col < VOCAB)
      float* orow = OUT + (size_t)(m0 + rowl + r) * VOCAB;
#pragma unroll
      for (int j = 0; j < 4; ++j)
        if (vld[j]) orow[n0 + wn + j * 16 + cc] = v[j];

      // thread-local stats over valid cols
      float tm = -INFINITY, tt = 0.f;
#pragma unroll
      for (int j = 0; j < 4; ++j) {
        tm = fmaxf(tm, vld[j] ? v[j] : -INFINITY);
        tt += vld[j] ? v[j] : 0.f;
      }
      float te = 0.f;
#pragma unroll
      for (int j = 0; j < 4; ++j)
        te += vld[j] ? __expf(v[j] - tm) : 0.f;

      // merge across the 16 lanes holding this row (xor 1,2,4,8 stays in-group)
#pragma unroll
      for (int off = 1; off < 16; off <<= 1) {
        float om = __shfl_xor(tm, off);
        float os = __shfl_xor(te, off);
        float ot = __shfl_xor(tt, off);
        float nm = fmaxf(tm, om);
        te = te * __expf(tm - nm) + os * __expf(om - nm);
        tm = nm;
        tt += ot;
      }
      if (cc == 0) {
        f32x4 p; p[0] = tm; p[1] = te; p[2] = tt; p[3] = 0.f;
        sred[rowl + r][wave & 1] = p;
      }
    }
  }

  __syncthreads();
  if (tid < 128) {
    f32x4 a = sred[tid][0], b = sred[tid][1];
    float nm = fmaxf(a[0], b[0]);
    f32x4 p;
    p[0] = nm;
    p[1] = a[1] * __expf(a[0] - nm) + b[1] * __expf(b[0] - nm);
    p[2] = a[2] + b[2];
    p[3] = 0.f;
    partial[(size_t)(m0 + tid) * NTILE + n_tile] = p;
  }
}

// ---------------- finalize: merge partials per row, closed-form KL ----------------
__global__ __launch_bounds__(128)
void finalize_loss(const f32x4* __restrict__ partial, const float* __restrict__ S,
                   const int* __restrict__ labels, float* __restrict__ loss)
{
  const int row = blockIdx.x;
  const int tid = threadIdx.x;

  float m = -INFINITY, s = 0.f, t = 0.f;
  for (int nt = tid; nt < NTILE; nt += 128) {
    f32x4 p = partial[(size_t)row * NTILE + nt];
    float nm = fmaxf(m, p[0]);
    s = s * __expf(m - nm) + p[1] * __expf(p[0] - nm);
    m = nm;
    t += p[2];
  }
#pragma unroll
  for (int off = 1; off < 64; off <<= 1) {
    float om = __shfl_xor(m, off);
    float os = __shfl_xor(s, off);
    t += __shfl_xor(t, off);
    float nm = fmaxf(m, om);
    s = s * __expf(m - nm) + os * __expf(om - nm);
    m = nm;
  }
  __shared__ float red[6];
  if ((tid & 63) == 0) { int w = tid >> 6; red[w * 3] = m; red[w * 3 + 1] = s; red[w * 3 + 2] = t; }
  __syncthreads();
  if (tid == 0) {
    float m2 = red[3], s2 = red[4];
    float nm = fmaxf(red[0], m2);
    float S_ = red[1] * __expf(red[0] - nm) + s2 * __expf(m2 - nm);
    float T_ = red[2] + red[5];
    const int lbl = labels[row];
    if (lbl != PAD_ID) {
      const float* p = S + (size_t)row * VOCAB;
      const float x_lbl = p[lbl];
      const float x_pad = p[PAD_ID];
      const float logZ = nm + logf(S_);
      const float sv   = 0.1f / (float)(VOCAB - 2);
      const float conf = 0.9f;
      const float plogp = 0.1f * logf(sv) + conf * logf(conf);
      const float plogq = sv * (T_ - x_pad - x_lbl) + conf * x_lbl - logZ;
      atomicAdd(loss, (plogp - plogq) * (1.0f / N_TOK));
    }
  }
}

// ---------------- mid-tier GEMM (no fusion) ----------------
__global__ __launch_bounds__(256)
void gemm_scores_bf16(const unsigned short* __restrict__ Xb, const unsigned short* __restrict__ Wb,
                      const float* __restrict__ bias, float* __restrict__ OUT)
{
  const int tid  = threadIdx.x;
  const int lane = tid & 63;
  const int wave = tid >> 6;
  const int bid = blockIdx.x;
  const int sw  = (bid & 7) * CPX + (bid >> 3);
  const int m0 = (sw & 15) * 128;
  const int n0 = (sw >> 4) * 128;
  const int wm = (wave >> 1) * 64;
  const int wn = (wave & 1) * 64;

  __shared__ __attribute__((aligned(16))) unsigned short As[128 * 32];
  __shared__ __attribute__((aligned(16))) unsigned short Bs[128 * 32];

  f32x4 acc[4][4] = {};
  const int frow = lane & 15;
  const int fk   = (lane >> 4) * 8;
  const int srow = (lane >> 2);
  const int scol = (lane & 3) * 8;

  for (int kt = 0; kt < D_MODEL / 32; ++kt) {
    const int k0 = kt * 32;
    __syncthreads();
#pragma unroll
    for (int i = 0; i < 2; ++i) {
      const int r = wave * 32 + i * 16;
      gload_lds16(Xb + (size_t)(m0 + r + srow) * D_MODEL + k0 + scol, &As[r * 32]);
      gload_lds16(Wb + (size_t)(n0 + r + srow) * D_MODEL + k0 + scol, &Bs[r * 32]);
    }
    __syncthreads();

    bf16x8 afrag[4], bfrag[4];
#pragma unroll
    for (int i = 0; i < 4; ++i)
      afrag[i] = *(const bf16x8*)&As[(wm + i * 16 + frow) * 32 + fk];
#pragma unroll
    for (int j = 0; j < 4; ++j)
      bfrag[j] = *(const bf16x8*)&Bs[(wn + j * 16 + frow) * 32 + fk];
#pragma unroll
    for (int i = 0; i < 4; ++i)
#pragma unroll
      for (int j = 0; j < 4; ++j)
        acc[i][j] = __builtin_amdgcn_mfma_f32_16x16x32_bf16(afrag[i], bfrag[j], acc[i][j], 0, 0, 0);
  }

  const int r4 = (lane >> 4) << 2;
  const int cc = lane & 15;
#pragma unroll
  for (int j = 0; j < 4; ++j) {
    const int col = n0 + wn + j * 16 + cc;
    if (col < VOCAB) {
      const float bj = bias[col];
#pragma unroll
      for (int i = 0; i < 4; ++i) {
        const int row = m0 + wm + i * 16 + r4;
        float* o = OUT + (size_t)row * VOCAB + col;
#pragma unroll
        for (int r = 0; r < 4; ++r)
          o[(size_t)r * VOCAB] = acc[i][j][r] + bj;
      }
    }
  }
}

// ---------------- fallback GEMM: f32 inputs, reg-staged ----------------
__global__ __launch_bounds__(256)
void gemm_scores(const float* __restrict__ X, const float* __restrict__ W,
                 const float* __restrict__ bias, float* __restrict__ OUT)
{
  const int tid  = threadIdx.x;
  const int lane = tid & 63;
  const int wave = tid >> 6;
  const int m0 = blockIdx.y * 128;
  const int n0 = blockIdx.x * 128;
  const int wm = (wave >> 1) * 64;
  const int wn = (wave & 1) * 64;

  __shared__ __attribute__((aligned(16))) unsigned short As[128 * 32];
  __shared__ __attribute__((aligned(16))) unsigned short Bs[128 * 32];

  f32x4 acc[4][4] = {};
  const int frow = lane & 15;
  const int fk   = (lane >> 4) * 8;

  for (int kt = 0; kt < D_MODEL / 32; ++kt) {
    const int k0 = kt * 32;
    f32x4 av[4], bv[4];
#pragma unroll
    for (int i = 0; i < 4; ++i) {
      const int idx = tid + (i << 8);
      const int r = idx >> 3;
      const int c = (idx & 7) << 2;
      av[i] = *(const f32x4*)(X + (size_t)(m0 + r) * D_MODEL + k0 + c);
      int wr = n0 + r; if (wr > VOCAB - 1) wr = VOCAB - 1;
      bv[i] = *(const f32x4*)(W + (size_t)wr * D_MODEL + k0 + c);
    }
    __syncthreads();
#pragma unroll
    for (int i = 0; i < 4; ++i) {
      const int idx = tid + (i << 8);
      const int r = idx >> 3;
      const int c = (idx & 7) << 2;
      u32x2 pa, pb;
      pa[0] = pack2bf(av[i][0], av[i][1]);
      pa[1] = pack2bf(av[i][2], av[i][3]);
      pb[0] = pack2bf(bv[i][0], bv[i][1]);
      pb[1] = pack2bf(bv[i][2], bv[i][3]);
      *(u32x2*)&As[r * 32 + c] = pa;
      *(u32x2*)&Bs[r * 32 + c] = pb;
    }
    __syncthreads();

    bf16x8 afrag[4], bfrag[4];
#pragma unroll
    for (int i = 0; i < 4; ++i)
      afrag[i] = *(const bf16x8*)&As[(wm + i * 16 + frow) * 32 + fk];
#pragma unroll
    for (int j = 0; j < 4; ++j)
      bfrag[j] = *(const bf16x8*)&Bs[(wn + j * 16 + frow) * 32 + fk];
#pragma unroll
    for (int i = 0; i < 4; ++i)
#pragma unroll
      for (int j = 0; j < 4; ++j)
        acc[i][j] = __builtin_amdgcn_mfma_f32_16x16x32_bf16(afrag[i], bfrag[j], acc[i][j], 0, 0, 0);
  }

  const int r4 = (lane >> 4) << 2;
  const int cc = lane & 15;
#pragma unroll
  for (int j = 0; j < 4; ++j) {
    const int col = n0 + wn + j * 16 + cc;
    if (col < VOCAB) {
      const float bj = bias[col];
#pragma unroll
      for (int i = 0; i < 4; ++i) {
        const int row = m0 + wm + i * 16 + r4;
        float* o = OUT + (size_t)row * VOCAB + col;
#pragma unroll
        for (int r = 0; r < 4; ++r)
          o[(size_t)r * VOCAB] = acc[i][j][r] + bj;
      }
    }
  }
}

// ---------------- standalone row stats (mid-tier path) ----------------
__global__ __launch_bounds__(256)
void row_stats_loss(const float* __restrict__ S, const int* __restrict__ labels,
                    float* __restrict__ loss)
{
  const int row = blockIdx.x;
  const int tid = threadIdx.x;
  const float* p = S + (size_t)row * VOCAB;

  float m = -INFINITY, s = 0.f, tot = 0.f;
  const int head = (4 - (row & 3)) & 3;
  if (tid < head) { float x = p[tid]; tot = x; m = x; s = 1.f; }
  const int nvec = (VOCAB - head) >> 2;
  const float* pv = p + head;
  for (int i = tid; i < nvec; i += 256) {
    f32x4 x4 = *(const f32x4*)(pv + 4 * i);
#pragma unroll
    for (int e = 0; e < 4; ++e) {
      float x = x4[e];
      tot += x;
      float nm = fmaxf(m, x);
      if (nm > m) { s *= __expf(m - nm); m = nm; }
      s += __expf(x - m);
    }
  }
  const int tbase = head + 4 * nvec;
  if (tid < VOCAB - tbase) {
    float x = p[tbase + tid];
    tot += x;
    float nm = fmaxf(m, x);
    if (nm > m) { s *= __expf(m - nm); m = nm; }
    s += __expf(x - m);
  }
#pragma unroll
  for (int off = 1; off < 64; off <<= 1) {
    float om = __shfl_xor(m, off);
    float os = __shfl_xor(s, off);
    tot += __shfl_xor(tot, off);
    float nm = fmaxf(m, om);
    s = s * __expf(m - nm) + os * __expf(om - nm);
    m = nm;
  }
  __shared__ float red[12];
  const int wave = tid >> 6;
  if ((tid & 63) == 0) { red[wave] = m; red[4 + wave] = s; red[8 + wave] = tot; }
  __syncthreads();
  if (tid == 0) {
    m = red[0]; s = red[4]; tot = red[8];
    for (int w = 1; w < 4; ++w) {
      float om = red[w], os = red[4 + w];
      float nm = fmaxf(m, om);
      s = s * __expf(m - nm) + os * __expf(om - nm);
      m = nm;
      tot += red[8 + w];
    }
    const int lbl = labels[row];
    if (lbl != PAD_ID) {
      const float x_lbl = p[lbl];
      const float x_pad = p[PAD_ID];
      const float logZ = m + logf(s);
      const float sv   = 0.1f / (float)(VOCAB - 2);
      const float conf = 0.9f;
      const float plogp = 0.1f * logf(sv) + conf * logf(conf);
      const float plogq = sv * (tot - x_pad - x_lbl) + conf * x_lbl - logZ;
      atomicAdd(loss, (plogp - plogq) * (1.0f / N_TOK));
    }
  }
}

__global__ void zero_loss(float* loss) { *loss = 0.f; }

extern "C" void kernel_launch(void* const* d_in, const int* in_sizes, int n_in,
                              void* d_out, int out_size, void* d_ws, size_t ws_size,
                              hipStream_t stream) {
  const float* X      = (const float*)d_in[0];
  const float* W      = (const float*)d_in[1];
  const float* bias   = (const float*)d_in[2];
  const int*   labels = (const int*)d_in[3];
  float* out  = (float*)d_out;
  float* loss = out + (size_t)N_TOK * VOCAB;

  zero_loss<<<1, 1, 0, stream>>>(loss);

  const size_t wb_elems = (size_t)VPAD * D_MODEL;
  const size_t xb_elems = (size_t)N_TOK * D_MODEL;
  const size_t need_gemm = (wb_elems + xb_elems) * sizeof(unsigned short);
  const size_t part_bytes = (size_t)N_TOK * NTILE * sizeof(f32x4);   // 12.9 MB
  const size_t need_fused = need_gemm + part_bytes;

  if (ws_size >= need_gemm) {
    unsigned short* Wb = (unsigned short*)d_ws;
    unsigned short* Xb = Wb + wb_elems;
    cvt_f32_bf16<<<2048, 256, 0, stream>>>(W, Wb, (int)((size_t)VOCAB * D_MODEL / 4));
    {
      const int padn4 = (int)(((size_t)(VPAD - VOCAB) * D_MODEL) / 4);
      zero_pad_rows<<<(padn4 + 255) / 256, 256, 0, stream>>>(Wb + (size_t)VOCAB * D_MODEL, padn4);
    }
    cvt_f32_bf16<<<512, 256, 0, stream>>>(X, Xb, (int)(xb_elems / 4));

    if (ws_size >= need_fused) {
      f32x4* partial = (f32x4*)(Xb + xb_elems);
      gemm_scores_fused<<<NWG, 256, 0, stream>>>(Xb, Wb, bias, out, partial);
      finalize_loss<<<N_TOK, 128, 0, stream>>>(partial, out, labels, loss);
    } else {
      gemm_scores_bf16<<<NWG, 256, 0, stream>>>(Xb, Wb, bias, out);
      row_stats_loss<<<N_TOK, 256, 0, stream>>>(out, labels, loss);
    }
  } else {
    dim3 grid(VPAD / 128, N_TOK / 128);
    gemm_scores<<<grid, 256, 0, stream>>>(X, W, bias, out);
    row_stats_loss<<<N_TOK, 256, 0, stream>>>(out, labels, loss);
  }
}